// Round 12
// baseline (603.125 us; speedup 1.0000x reference)
//
#include <hip/hip_runtime.h>
#include <hip/hip_fp16.h>

#define GRID_N 4096
#define NTHREADS 256
#define NSLAB 8
#define SLAB_SHIFT 9            // slab = x1 >> 9
#define CHUNK 2048              // points per partition/unperm block
#define CRANKS 256              // gather blocks per bucket

typedef float f32x4 __attribute__((ext_vector_type(4)));
typedef unsigned int u32x4 __attribute__((ext_vector_type(4)));

__device__ __forceinline__ float h2f(unsigned short u) {
    union { __half h; unsigned short u; } cv; cv.u = u; return __half2float(cv.h);
}
__device__ __forceinline__ unsigned short f2h(float f) {
    union { __half h; unsigned short u; } cv; cv.h = __float2half(f); return cv.u;
}

// meta layout (u32): [0..8] start[9]; [16..23] cnt/cursor[8]
__global__ void zero_meta_kernel(float* out, unsigned int* meta) {
    if (threadIdx.x == 0) out[0] = 0.0f;
    if (threadIdx.x < 8) meta[16 + threadIdx.x] = 0u;
}

// ---- Phase A: fp16 grid H (32 MB), normal stores (cacheable) ----
__global__ __launch_bounds__(NTHREADS) void build_h_kernel(
    const float* __restrict__ sdf, unsigned int* __restrict__ H2)
{
    const int tid = blockIdx.x * blockDim.x + threadIdx.x;
    const int stride = gridDim.x * blockDim.x;
    const f32x4* s4 = (const f32x4*)sdf;
    const int n4 = (GRID_N * GRID_N) / 4;
    for (int i = tid; i < n4; i += stride) {
        f32x4 v = __builtin_nontemporal_load(&s4[i]);
        unsigned int lo = (unsigned int)f2h(v.x) | ((unsigned int)f2h(v.y) << 16);
        unsigned int hi = (unsigned int)f2h(v.z) | ((unsigned int)f2h(v.w) << 16);
        H2[2 * i] = lo;
        H2[2 * i + 1] = hi;
    }
}

// ---- Phase B1: slab histogram ----
__global__ __launch_bounds__(NTHREADS) void count_kernel(
    const float* __restrict__ x, unsigned int* __restrict__ meta, int n)
{
    __shared__ unsigned int lcnt[NSLAB];
    if (threadIdx.x < NSLAB) lcnt[threadIdx.x] = 0u;
    __syncthreads();
    const int tid = blockIdx.x * blockDim.x + threadIdx.x;
    const int stride = gridDim.x * blockDim.x;
    const f32x4* x4 = (const f32x4*)x;
    const int n4 = n >> 2;
    for (int i = tid; i < n4; i += stride) {
        f32x4 xv = __builtin_nontemporal_load(&x4[i]);
        float xs[4] = {xv.x, xv.y, xv.z, xv.w};
#pragma unroll
        for (int k = 0; k < 4; ++k) {
            int b = min((int)xs[k], GRID_N - 2) >> SLAB_SHIFT;
            atomicAdd(&lcnt[b], 1u);
        }
    }
    __syncthreads();
    if (threadIdx.x < NSLAB) atomicAdd(&meta[16 + threadIdx.x], lcnt[threadIdx.x]);
}

// ---- scan: start[] prefix; cursor reset to start ----
__global__ void scan_kernel(unsigned int* meta) {
    if (threadIdx.x == 0) {
        unsigned int acc = 0;
        for (int s = 0; s < NSLAB; ++s) {
            unsigned int c = meta[16 + s];
            meta[s] = acc;
            meta[16 + s] = acc;   // cursor = start
            acc += c;
        }
        meta[NSLAB] = acc;
    }
}

// ---- Phase B3: partition scatter ----
// record (8B): y1:u16 | x1:u16 | t:f16 | u:f16 ; idx[i] = bucket position
__global__ __launch_bounds__(NTHREADS) void part_kernel(
    const float* __restrict__ x, const float* __restrict__ y,
    unsigned long long* __restrict__ R, unsigned int* __restrict__ idx,
    unsigned int* __restrict__ meta, int n)
{
    __shared__ unsigned int lcnt[NSLAB];
    __shared__ unsigned int sbase[NSLAB];
    if (threadIdx.x < NSLAB) lcnt[threadIdx.x] = 0u;
    __syncthreads();

    const int i0 = blockIdx.x * CHUNK + threadIdx.x * 8;
    float xs[8], ys[8];
    int bk[8]; unsigned int rk[8];
    bool valid[8];
    const f32x4* x4 = (const f32x4*)x;
    const f32x4* y4 = (const f32x4*)y;

#pragma unroll
    for (int k = 0; k < 8; ++k) valid[k] = (i0 + k) < n;
    if (i0 + 7 < n) {
        f32x4 xa = __builtin_nontemporal_load(&x4[i0 / 4]);
        f32x4 xb = __builtin_nontemporal_load(&x4[i0 / 4 + 1]);
        f32x4 ya = __builtin_nontemporal_load(&y4[i0 / 4]);
        f32x4 yb = __builtin_nontemporal_load(&y4[i0 / 4 + 1]);
        xs[0]=xa.x; xs[1]=xa.y; xs[2]=xa.z; xs[3]=xa.w;
        xs[4]=xb.x; xs[5]=xb.y; xs[6]=xb.z; xs[7]=xb.w;
        ys[0]=ya.x; ys[1]=ya.y; ys[2]=ya.z; ys[3]=ya.w;
        ys[4]=yb.x; ys[5]=yb.y; ys[6]=yb.z; ys[7]=yb.w;
    } else {
#pragma unroll
        for (int k = 0; k < 8; ++k) {
            xs[k] = valid[k] ? x[i0 + k] : 0.0f;
            ys[k] = valid[k] ? y[i0 + k] : 0.0f;
        }
    }

#pragma unroll
    for (int k = 0; k < 8; ++k) {
        int x1 = min((int)xs[k], GRID_N - 2);
        bk[k] = x1 >> SLAB_SHIFT;
        if (valid[k]) rk[k] = atomicAdd(&lcnt[bk[k]], 1u);
    }
    __syncthreads();
    if (threadIdx.x < NSLAB)
        sbase[threadIdx.x] = atomicAdd(&meta[16 + threadIdx.x], lcnt[threadIdx.x]);
    __syncthreads();

#pragma unroll
    for (int k = 0; k < 8; ++k) {
        if (!valid[k]) continue;
        int x1 = min((int)xs[k], GRID_N - 2);
        int y1 = min((int)ys[k], GRID_N - 2);
        unsigned short t16 = f2h(xs[k] - (float)x1);
        unsigned short u16 = f2h(ys[k] - (float)y1);
        unsigned long long rec = (unsigned long long)(unsigned short)y1
                               | ((unsigned long long)(unsigned short)x1 << 16)
                               | ((unsigned long long)t16 << 32)
                               | ((unsigned long long)u16 << 48);
        unsigned int pos = sbase[bk[k]] + rk[k];
        R[pos] = rec;
        idx[i0 + k] = pos;
    }
}

// ---- Phase C: per-slab gather (XCD-L2 resident), val -> R[j] low 4B ----
__global__ __launch_bounds__(NTHREADS) void gather_kernel(
    unsigned long long* __restrict__ R,
    const unsigned int* __restrict__ H2,   // fp16-pair dwords
    const unsigned int* __restrict__ meta,
    float* __restrict__ out)
{
    const int s = blockIdx.x & (NSLAB - 1);
    const int rk = blockIdx.x >> 3;
    const unsigned int jb = meta[s];
    const unsigned int je = meta[s + 1];
    const unsigned int step = (gridDim.x >> 3) * NTHREADS * 2;
    float lsum = 0.0f;

    for (unsigned int j = jb + (rk * NTHREADS + threadIdx.x) * 2; j < je; j += step) {
#pragma unroll
        for (int q = 0; q < 2; ++q) {
            unsigned int jj = j + q;
            if (jj >= je) break;
            unsigned long long rec = __builtin_nontemporal_load(&R[jj]);
            int y1 = (int)(rec & 0xffffu);
            int x1 = (int)((rec >> 16) & 0xffffu);
            float t = h2f((unsigned short)(rec >> 32));
            float u = h2f((unsigned short)(rec >> 48));
            unsigned off0 = ((unsigned)x1 << 12) + (unsigned)y1;
            unsigned off1 = off0 + GRID_N;
            unsigned d0  = H2[off0 >> 1];
            unsigned d0b = H2[(off0 + 1) >> 1];
            unsigned d1  = H2[off1 >> 1];
            unsigned d1b = H2[(off1 + 1) >> 1];
            bool odd = (off0 & 1u) != 0;
            unsigned short v11 = odd ? (unsigned short)(d0 >> 16) : (unsigned short)d0;
            unsigned short v12 = odd ? (unsigned short)d0b        : (unsigned short)(d0 >> 16);
            unsigned short v21 = odd ? (unsigned short)(d1 >> 16) : (unsigned short)d1;
            unsigned short v22 = odd ? (unsigned short)d1b        : (unsigned short)(d1 >> 16);
            float f11 = h2f(v11), f21 = h2f(v21), f12 = h2f(v12), f22 = h2f(v22);
            float a = f11 + t * (f21 - f11);
            float b = f12 + t * (f22 - f12);
            float val = a + u * (b - a);
            val = fminf(0.0f, fmaxf(-1000.0f, val));
            lsum += val;
            *(float*)(&R[jj]) = val;   // low 4B of the record slot
        }
    }

#pragma unroll
    for (int off = 32; off > 0; off >>= 1)
        lsum += __shfl_down(lsum, off);
    __shared__ float wsum[NTHREADS / 64];
    const int lane = threadIdx.x & 63;
    const int wid = threadIdx.x >> 6;
    if (lane == 0) wsum[wid] = lsum;
    __syncthreads();
    if (threadIdx.x == 0) {
        float bsum = 0.0f;
#pragma unroll
        for (int w = 0; w < NTHREADS / 64; ++w) bsum += wsum[w];
        atomicAdd(out, bsum);
    }
}

// ---- Phase D: un-permute via idx (quasi-sequential val reads) ----
__global__ __launch_bounds__(NTHREADS) void unperm_kernel(
    const unsigned int* __restrict__ idx,
    const unsigned long long* __restrict__ R,
    float* __restrict__ out, int n)
{
    const int i0 = blockIdx.x * CHUNK + threadIdx.x * 8;
    float* vals_out = out + 1;
    if (i0 + 7 < n) {
        u32x4 ia = __builtin_nontemporal_load((const u32x4*)(idx + i0));
        u32x4 ib = __builtin_nontemporal_load((const u32x4*)(idx + i0 + 4));
        unsigned int id[8] = {ia.x, ia.y, ia.z, ia.w, ib.x, ib.y, ib.z, ib.w};
        float v[8];
#pragma unroll
        for (int k = 0; k < 8; ++k)
            v[k] = *(const float*)(&R[id[k]]);   // normal load: L2 reuse
#pragma unroll
        for (int k = 0; k < 8; ++k)
            __builtin_nontemporal_store(v[k], &vals_out[i0 + k]);
    } else {
        for (int k = 0; k < 8; ++k) {
            int i = i0 + k;
            if (i < n) vals_out[i] = *(const float*)(&R[idx[i]]);
        }
    }
}

// ================= proven fallback: packed15 (R11, 360 µs) =================
#define PB 273
#define ROW_HALFS (PB * 32)
#define NROWS (GRID_N - 1)

__global__ __launch_bounds__(NTHREADS) void build_p15_kernel(
    const float* __restrict__ sdf, unsigned int* __restrict__ P)
{
    const int r = blockIdx.x;
    const float* row0 = sdf + (size_t)r * GRID_N;
    const float* row1 = row0 + GRID_N;
    unsigned int* prow = P + (size_t)r * (ROW_HALFS / 2);
    const int ndw = PB * 16;
    for (int d = threadIdx.x; d < ndw; d += NTHREADS) {
        int b = d >> 4;
        int s = d & 15;
        int c = 15 * b + s;
        float a = row0[c];
        float e = row1[c];
        unsigned int v = (unsigned int)f2h(a) | ((unsigned int)f2h(e) << 16);
        __builtin_nontemporal_store(v, &prow[d]);
    }
}

__global__ __launch_bounds__(NTHREADS) void sdf_bilinear_p15_kernel(
    const float* __restrict__ x,
    const float* __restrict__ y,
    const unsigned int* __restrict__ P,
    float* __restrict__ out,
    int n8)
{
    const int tid = blockIdx.x * blockDim.x + threadIdx.x;
    const int stride = gridDim.x * blockDim.x;
    float lsum = 0.0f;
    const f32x4* x4 = (const f32x4*)x;
    const f32x4* y4 = (const f32x4*)y;
    float* vals_out = out + 1;

    for (int i = tid; i < n8; i += stride) {
        const int g0 = 2 * i, g1 = 2 * i + 1;
        f32x4 xa = __builtin_nontemporal_load(&x4[g0]);
        f32x4 xb = __builtin_nontemporal_load(&x4[g1]);
        f32x4 ya = __builtin_nontemporal_load(&y4[g0]);
        f32x4 yb = __builtin_nontemporal_load(&y4[g1]);
        float xs[8] = {xa.x, xa.y, xa.z, xa.w, xb.x, xb.y, xb.z, xb.w};
        float ys[8] = {ya.x, ya.y, ya.z, ya.w, yb.x, yb.y, yb.z, yb.w};
        unsigned int d0[8], d1[8];
        float t[8], u[8];
#pragma unroll
        for (int k = 0; k < 8; ++k) {
            float xi = xs[k], yi = ys[k];
            int x1 = min((int)xi, GRID_N - 2);
            int y1 = min((int)yi, GRID_N - 2);
            t[k] = xi - (float)x1;
            u[k] = yi - (float)y1;
            int b = (y1 * 4370) >> 16;
            int s = y1 - 15 * b;
            const unsigned int* blk = P + (size_t)x1 * (ROW_HALFS / 2) + (b << 4) + s;
            d0[k] = blk[0];
            d1[k] = blk[1];
        }
        float res[8];
#pragma unroll
        for (int k = 0; k < 8; ++k) {
            float v11 = h2f((unsigned short)d0[k]);
            float v21 = h2f((unsigned short)(d0[k] >> 16));
            float v12 = h2f((unsigned short)d1[k]);
            float v22 = h2f((unsigned short)(d1[k] >> 16));
            float a = v11 + t[k] * (v21 - v11);
            float b2 = v12 + t[k] * (v22 - v12);
            float val = a + u[k] * (b2 - a);
            val = fminf(0.0f, fmaxf(-1000.0f, val));
            res[k] = val;
            lsum += val;
        }
        int base = g0 * 4;
#pragma unroll
        for (int k = 0; k < 8; ++k)
            __builtin_nontemporal_store(res[k], &vals_out[base + k]);
    }

#pragma unroll
    for (int off = 32; off > 0; off >>= 1)
        lsum += __shfl_down(lsum, off);
    __shared__ float wsum[NTHREADS / 64];
    const int lane = threadIdx.x & 63;
    const int wid = threadIdx.x >> 6;
    if (lane == 0) wsum[wid] = lsum;
    __syncthreads();
    if (threadIdx.x == 0) {
        float bsum = 0.0f;
#pragma unroll
        for (int w = 0; w < NTHREADS / 64; ++w) bsum += wsum[w];
        atomicAdd(out, bsum);
    }
}

__global__ void zero_loss_kernel(float* out) {
    if (threadIdx.x == 0) out[0] = 0.0f;
}

// ---------------- direct fallback (no workspace) ----------------
__global__ __launch_bounds__(NTHREADS) void sdf_bilinear_direct_kernel(
    const float* __restrict__ x,
    const float* __restrict__ y,
    const float* __restrict__ sdf,
    float* __restrict__ out,
    int n4)
{
    const int tid = blockIdx.x * blockDim.x + threadIdx.x;
    const int stride = gridDim.x * blockDim.x;
    float lsum = 0.0f;
    const f32x4* x4 = (const f32x4*)x;
    const f32x4* y4 = (const f32x4*)y;
    float* vals_out = out + 1;
    for (int i = tid; i < n4; i += stride) {
        f32x4 xv = x4[i];
        f32x4 yv = y4[i];
        float xs[4] = {xv.x, xv.y, xv.z, xv.w};
        float ys[4] = {yv.x, yv.y, yv.z, yv.w};
        float res[4];
#pragma unroll
        for (int k = 0; k < 4; ++k) {
            float xi = xs[k], yi = ys[k];
            int x1 = min((int)xi, GRID_N - 2);
            int y1 = min((int)yi, GRID_N - 2);
            float t = xi - (float)x1;
            float u = yi - (float)y1;
            const float* r1 = sdf + ((size_t)x1 << 12);
            const float* r2 = r1 + GRID_N;
            float v11 = r1[y1], v12 = r1[y1 + 1];
            float v21 = r2[y1], v22 = r2[y1 + 1];
            float a = v11 + t * (v21 - v11);
            float b = v12 + t * (v22 - v12);
            float val = a + u * (b - a);
            val = fminf(0.0f, fmaxf(-1000.0f, val));
            res[k] = val;
            lsum += val;
        }
        int base = i * 4;
        vals_out[base + 0] = res[0];
        vals_out[base + 1] = res[1];
        vals_out[base + 2] = res[2];
        vals_out[base + 3] = res[3];
    }
#pragma unroll
    for (int off = 32; off > 0; off >>= 1)
        lsum += __shfl_down(lsum, off);
    __shared__ float wsum[NTHREADS / 64];
    const int lane = threadIdx.x & 63;
    const int wid = threadIdx.x >> 6;
    if (lane == 0) wsum[wid] = lsum;
    __syncthreads();
    if (threadIdx.x == 0) {
        float bsum = 0.0f;
#pragma unroll
        for (int w = 0; w < NTHREADS / 64; ++w) bsum += wsum[w];
        atomicAdd(out, bsum);
    }
}

extern "C" void kernel_launch(void* const* d_in, const int* in_sizes, int n_in,
                              void* d_out, int out_size, void* d_ws, size_t ws_size,
                              hipStream_t stream) {
    const float* x = (const float*)d_in[0];
    const float* y = (const float*)d_in[1];
    const float* sdf = (const float*)d_in[2];
    float* out = (float*)d_out;
    int n = in_sizes[0];
    int n4 = n >> 2;
    int n8 = n >> 3;

    const size_t h_bytes = (size_t)GRID_N * GRID_N * 2;        // 32 MB
    const size_t r_bytes = (size_t)n * 8;                      // 134 MB
    const size_t idx_bytes = (size_t)n * 4;                    // 67 MB
    const size_t meta_bytes = 1024;
    const size_t pipe_bytes = h_bytes + r_bytes + idx_bytes + meta_bytes;  // ~235 MB
    const size_t p15_bytes = (size_t)NROWS * ROW_HALFS * 2;    // ~71.5 MB

    if (ws_size >= pipe_bytes) {
        char* base = (char*)d_ws;
        unsigned int* H2 = (unsigned int*)base;
        unsigned long long* R = (unsigned long long*)(base + h_bytes);
        unsigned int* idx = (unsigned int*)(base + h_bytes + r_bytes);
        unsigned int* meta = (unsigned int*)(base + h_bytes + r_bytes + idx_bytes);

        int nchunks = (n + CHUNK - 1) / CHUNK;
        zero_meta_kernel<<<1, 64, 0, stream>>>(out, meta);
        build_h_kernel<<<2048, NTHREADS, 0, stream>>>(sdf, H2);
        count_kernel<<<2048, NTHREADS, 0, stream>>>(x, meta, n);
        scan_kernel<<<1, 64, 0, stream>>>(meta);
        part_kernel<<<nchunks, NTHREADS, 0, stream>>>(x, y, R, idx, meta, n);
        gather_kernel<<<NSLAB * CRANKS, NTHREADS, 0, stream>>>(R, H2, meta, out);
        unperm_kernel<<<nchunks, NTHREADS, 0, stream>>>(idx, R, out, n);
    } else if (ws_size >= p15_bytes) {
        unsigned int* P = (unsigned int*)d_ws;
        zero_loss_kernel<<<1, 64, 0, stream>>>(out);
        build_p15_kernel<<<NROWS, NTHREADS, 0, stream>>>(sdf, P);
        int nblocks = (n8 + NTHREADS - 1) / NTHREADS;
        sdf_bilinear_p15_kernel<<<nblocks, NTHREADS, 0, stream>>>(x, y, P, out, n8);
    } else {
        zero_loss_kernel<<<1, 64, 0, stream>>>(out);
        sdf_bilinear_direct_kernel<<<2048, NTHREADS, 0, stream>>>(x, y, sdf, out, n4);
    }
}

// Round 13
// 362.923 us; speedup vs baseline: 1.6619x; 1.6619x over previous
//
#include <hip/hip_runtime.h>
#include <hip/hip_fp16.h>

#define GRID_N 4096
#define NTHREADS 256

// packed15 fp16 layout: each 64B block holds 16 fp16 column-pairs
// (v[r][c], v[r+1][c]) for c = 15b .. 15b+15 (col 15b+15 duplicated as slot 0
// of block b+1). Any bilinear span (c, c+1) with c = 15b+s, s<=14 lives in
// block b -> exactly ONE 64B line per point (provable minimum for a random
// point gather); footprint 71.5 MB.
#define PB 273                       // blocks per row: covers col <= 4095
#define ROW_HALFS (PB * 32)          // 8736 halfs = 17472 B per row
#define NROWS (GRID_N - 1)           // 4095

typedef float f32x4 __attribute__((ext_vector_type(4)));

__device__ __forceinline__ float h2f(unsigned short u) {
    union { __half h; unsigned short u; } cv; cv.u = u; return __half2float(cv.h);
}
__device__ __forceinline__ unsigned short f2h(float f) {
    union { __half h; unsigned short u; } cv; cv.h = __float2half(f); return cv.u;
}

__global__ void zero_loss_kernel(float* out) {
    if (threadIdx.x == 0) out[0] = 0.0f;
}

// ---------------- build packed15 grid ----------------
__global__ __launch_bounds__(NTHREADS) void build_p15_kernel(
    const float* __restrict__ sdf, unsigned int* __restrict__ P)
{
    const int r = blockIdx.x;                 // 0..4094
    const float* row0 = sdf + (size_t)r * GRID_N;
    const float* row1 = row0 + GRID_N;
    unsigned int* prow = P + (size_t)r * (ROW_HALFS / 2);
    const int ndw = PB * 16;                  // 4368 dwords per row
    for (int d = threadIdx.x; d < ndw; d += NTHREADS) {
        int b = d >> 4;
        int s = d & 15;
        int c = 15 * b + s;                   // <= 4095
        float a = row0[c];
        float e = row1[c];
        unsigned int v = (unsigned int)f2h(a) | ((unsigned int)f2h(e) << 16);
        __builtin_nontemporal_store(v, &prow[d]);
    }
}

// ---------------- main: 4 pts/thread, one 64B line per point ----------------
__global__ __launch_bounds__(NTHREADS) void sdf_bilinear_p15_kernel(
    const float* __restrict__ x,
    const float* __restrict__ y,
    const unsigned int* __restrict__ P,   // dword = fp16 pair
    float* __restrict__ out,
    int n4)
{
    const int tid = blockIdx.x * blockDim.x + threadIdx.x;
    const int stride = gridDim.x * blockDim.x;
    float lsum = 0.0f;

    const f32x4* x4 = (const f32x4*)x;
    const f32x4* y4 = (const f32x4*)y;
    float* vals_out = out + 1;

    for (int i = tid; i < n4; i += stride) {
        f32x4 xv = __builtin_nontemporal_load(&x4[i]);
        f32x4 yv = __builtin_nontemporal_load(&y4[i]);
        float xs[4] = {xv.x, xv.y, xv.z, xv.w};
        float ys[4] = {yv.x, yv.y, yv.z, yv.w};

        unsigned int d0[4], d1[4];
        float t[4], u[4];
#pragma unroll
        for (int k = 0; k < 4; ++k) {
            float xi = xs[k];
            float yi = ys[k];
            int x1 = min((int)xi, GRID_N - 2);   // inputs >= 0
            int y1 = min((int)yi, GRID_N - 2);
            t[k] = xi - (float)x1;
            u[k] = yi - (float)y1;
            int b = (y1 * 4370) >> 16;           // exact y1/15 for y1 <= 4094
            int s = y1 - 15 * b;                 // 0..14
            const unsigned int* blk = P + (size_t)x1 * (ROW_HALFS / 2) + (b << 4) + s;
            d0[k] = blk[0];   // (v11, v21)
            d1[k] = blk[1];   // (v12, v22) — same 64B line, guaranteed
        }

        float res[4];
#pragma unroll
        for (int k = 0; k < 4; ++k) {
            float v11 = h2f((unsigned short)d0[k]);
            float v21 = h2f((unsigned short)(d0[k] >> 16));
            float v12 = h2f((unsigned short)d1[k]);
            float v22 = h2f((unsigned short)(d1[k] >> 16));
            float a = v11 + t[k] * (v21 - v11);
            float b2 = v12 + t[k] * (v22 - v12);
            float val = a + u[k] * (b2 - a);
            val = fminf(0.0f, fmaxf(-1000.0f, val));
            res[k] = val;
            lsum += val;
        }

        int base = i * 4;
        __builtin_nontemporal_store(res[0], &vals_out[base + 0]);
        __builtin_nontemporal_store(res[1], &vals_out[base + 1]);
        __builtin_nontemporal_store(res[2], &vals_out[base + 2]);
        __builtin_nontemporal_store(res[3], &vals_out[base + 3]);
    }

#pragma unroll
    for (int off = 32; off > 0; off >>= 1)
        lsum += __shfl_down(lsum, off);

    __shared__ float wsum[NTHREADS / 64];
    const int lane = threadIdx.x & 63;
    const int wid = threadIdx.x >> 6;
    if (lane == 0) wsum[wid] = lsum;
    __syncthreads();
    if (threadIdx.x == 0) {
        float bsum = 0.0f;
#pragma unroll
        for (int w = 0; w < NTHREADS / 64; ++w) bsum += wsum[w];
        atomicAdd(out, bsum);
    }
}

// ---------------- direct fallback (no workspace) ----------------
__global__ __launch_bounds__(NTHREADS) void sdf_bilinear_direct_kernel(
    const float* __restrict__ x,
    const float* __restrict__ y,
    const float* __restrict__ sdf,
    float* __restrict__ out,
    int n4)
{
    const int tid = blockIdx.x * blockDim.x + threadIdx.x;
    const int stride = gridDim.x * blockDim.x;
    float lsum = 0.0f;
    const f32x4* x4 = (const f32x4*)x;
    const f32x4* y4 = (const f32x4*)y;
    float* vals_out = out + 1;

    for (int i = tid; i < n4; i += stride) {
        f32x4 xv = x4[i];
        f32x4 yv = y4[i];
        float xs[4] = {xv.x, xv.y, xv.z, xv.w};
        float ys[4] = {yv.x, yv.y, yv.z, yv.w};
        float res[4];
#pragma unroll
        for (int k = 0; k < 4; ++k) {
            float xi = xs[k], yi = ys[k];
            int x1 = min((int)xi, GRID_N - 2);
            int y1 = min((int)yi, GRID_N - 2);
            float t = xi - (float)x1;
            float u = yi - (float)y1;
            const float* r1 = sdf + ((size_t)x1 << 12);
            const float* r2 = r1 + GRID_N;
            float v11 = r1[y1], v12 = r1[y1 + 1];
            float v21 = r2[y1], v22 = r2[y1 + 1];
            float a = v11 + t * (v21 - v11);
            float b = v12 + t * (v22 - v12);
            float val = a + u * (b - a);
            val = fminf(0.0f, fmaxf(-1000.0f, val));
            res[k] = val;
            lsum += val;
        }
        int base = i * 4;
        vals_out[base + 0] = res[0];
        vals_out[base + 1] = res[1];
        vals_out[base + 2] = res[2];
        vals_out[base + 3] = res[3];
    }

#pragma unroll
    for (int off = 32; off > 0; off >>= 1)
        lsum += __shfl_down(lsum, off);

    __shared__ float wsum[NTHREADS / 64];
    const int lane = threadIdx.x & 63;
    const int wid = threadIdx.x >> 6;
    if (lane == 0) wsum[wid] = lsum;
    __syncthreads();
    if (threadIdx.x == 0) {
        float bsum = 0.0f;
#pragma unroll
        for (int w = 0; w < NTHREADS / 64; ++w) bsum += wsum[w];
        atomicAdd(out, bsum);
    }
}

extern "C" void kernel_launch(void* const* d_in, const int* in_sizes, int n_in,
                              void* d_out, int out_size, void* d_ws, size_t ws_size,
                              hipStream_t stream) {
    const float* x = (const float*)d_in[0];
    const float* y = (const float*)d_in[1];
    const float* sdf = (const float*)d_in[2];
    float* out = (float*)d_out;
    int n = in_sizes[0];
    int n4 = n >> 2;

    zero_loss_kernel<<<1, 64, 0, stream>>>(out);

    const size_t p15_bytes = (size_t)NROWS * ROW_HALFS * 2;   // ~71.5 MB

    if (ws_size >= p15_bytes) {
        unsigned int* P = (unsigned int*)d_ws;
        build_p15_kernel<<<NROWS, NTHREADS, 0, stream>>>(sdf, P);
        int nblocks = (n4 + NTHREADS - 1) / NTHREADS;  // one 4-pt group per thread
        sdf_bilinear_p15_kernel<<<nblocks, NTHREADS, 0, stream>>>(x, y, P, out, n4);
    } else {
        sdf_bilinear_direct_kernel<<<2048, NTHREADS, 0, stream>>>(x, y, sdf, out, n4);
    }
}